// Round 7
// baseline (343.737 us; speedup 1.0000x reference)
//
#include <hip/hip_runtime.h>

// DepthDeformConvPack on MI355X — round 7: deterministic split-K.
// r6 post-mortem: first-call validation PASSED (absmax 0.0078125) but the
// graph-replay re-validation failed — float atomicAdd split-K gives
// order-dependent (replay-varying) results. Fix: fixed-point int32 atomics
// into d_out (exact, commutative -> bit-identical across replays) + an
// in-place int->float finalize kernel. Scale 2^22: quant err 1.2e-7/partial,
// range |sum| < 512 (outputs O(1)).
// Structure otherwise identical to r6: split-K x4 (1024 blocks, 4/CU, full
// occupancy, zero sampling duplication), fused offset+mask kernel.

typedef __bf16 bf16x8 __attribute__((ext_vector_type(8)));
typedef float f32x4 __attribute__((ext_vector_type(4)));
typedef float float2_u __attribute__((ext_vector_type(2), aligned(4)));

#define FIXSCALE 4194304.0f            // 2^22
#define FIXINV   2.38418579101562e-7f  // 2^-22

__device__ __forceinline__ unsigned short f2bf(float f) {
  unsigned b = __float_as_uint(f);
  return (unsigned short)((b + 0x7fffu + ((b >> 16) & 1u)) >> 16);
}

// ---------------------------------------------------------------------------
// K0: weight fp32 -> bf16, natural (channel-major) layout k = c*9+tap
// ---------------------------------------------------------------------------
__global__ __launch_bounds__(256) void k_prep_weight(
    const float* __restrict__ w, unsigned short* __restrict__ wbf)
{
  const int i = blockIdx.x * 256 + threadIdx.x;   // 589824 total
  wbf[i] = f2bf(w[i]);
}

// ---------------------------------------------------------------------------
// K-fused: offset conv (320ch -> 18) THEN mask deform conv (64ch -> 9) for one
// (n, ho) row. 256 blocks, 512 threads = 8 waves.
// ---------------------------------------------------------------------------
__global__ __launch_bounds__(512) void k_offmask(
    const float* __restrict__ x, const float* __restrict__ depth,
    const float* __restrict__ off_w, const float* __restrict__ off_b,
    const float* __restrict__ mask_w, const float* __restrict__ mask_b,
    float* __restrict__ offs, float* __restrict__ mask)
{
  __shared__ float  redA[8][18][64];   // 36864 B
  __shared__ float  offsRow[18][64];   //  4608 B
  __shared__ float4 qw[9][64];         //  9216 B
  __shared__ int2   qi[9][64];         //  4608 B
  __shared__ float  redB[8][9][64];    // 18432 B

  const int n  = blockIdx.x >> 6;
  const int ho = blockIdx.x & 63;
  const int tid  = threadIdx.x;
  const int lane = tid & 63;          // wo
  const int wave = tid >> 6;          // 0..7

  // ---- phase A: offset conv ----
  float acc[18];
#pragma unroll
  for (int i = 0; i < 18; ++i) acc[i] = 0.f;

  const int c0 = __builtin_amdgcn_readfirstlane(wave * 40);
  for (int ci = 0; ci < 40; ++ci) {
    const int c = c0 + ci;
    const float* p = (c < 256) ? (x + (((n << 8) + c) << 12))
                               : (depth + (((n << 6) + (c - 256)) << 12));
    const float v0 = (ho > 0)  ? p[((ho - 1) << 6) + lane] : 0.f;
    const float v1 =             p[( ho      << 6) + lane];
    const float v2 = (ho < 63) ? p[((ho + 1) << 6) + lane] : 0.f;

    float v[9];
#pragma unroll
    for (int ky = 0; ky < 3; ++ky) {
      const float r = (ky == 0) ? v0 : ((ky == 1) ? v1 : v2);
#pragma unroll
      for (int kx = 0; kx < 3; ++kx) {
        const int src = lane + kx - 1;
        const float s = __shfl(r, src & 63);
        v[ky * 3 + kx] = (src >= 0 && src < 64) ? s : 0.f;
      }
    }
    const float* wp = off_w + c * 9;   // wave-uniform address
#pragma unroll
    for (int co = 0; co < 18; ++co) {
      const float* w = wp + co * 2880;
#pragma unroll
      for (int t = 0; t < 9; ++t) acc[co] += v[t] * w[t];
    }
  }
#pragma unroll
  for (int co = 0; co < 18; ++co) redA[wave][co][lane] = acc[co];
  __syncthreads();
  for (int o = tid; o < 18 * 64; o += 512) {
    const int co = o >> 6, wo = o & 63;
    float s = off_b[co];
#pragma unroll
    for (int w = 0; w < 8; ++w) s += redA[w][co][wo];
    offsRow[co][wo] = s;
    offs[((n * 18 + co) << 12) + (ho << 6) + wo] = s;
  }
  __syncthreads();

  // ---- phase B: sampling params from LDS offs row ----
  for (int e = tid; e < 576; e += 512) {
    const int tap = e >> 6, pl = e & 63;
    const float dy = offsRow[2 * tap][pl];
    const float dx = offsRow[2 * tap + 1][pl];
    const float yy = (float)(ho - 1 + tap / 3) + dy;
    const float xx = (float)(pl - 1 + tap % 3) + dx;
    const float y0f = floorf(yy), x0f = floorf(xx);
    const float ly = yy - y0f, lx = xx - x0f;
    const int y0 = (int)y0f, x0 = (int)x0f;
    const int y0c = min(max(y0, 0), 63);
    const int y1c = min(max(y0 + 1, 0), 63);
    const float fy0 = (y0 >= 0 && y0 < 64) ? 1.f : 0.f;
    const float fy1 = (y0 >= -1 && y0 < 63) ? 1.f : 0.f;
    const int x0c = min(max(x0, 0), 63);
    const int x1c = min(max(x0 + 1, 0), 63);
    const int bx  = min(max(x0, 0), 62);
    const float vx0 = (x0 >= 0 && x0 < 64) ? 1.f : 0.f;
    const float vx1 = (x0 >= -1 && x0 < 63) ? 1.f : 0.f;
    const float wl = (1.f - lx) * vx0 * ((x0c == bx) ? 1.f : 0.f)
                   + lx * vx1 * ((x1c == bx) ? 1.f : 0.f);
    const float wr = (1.f - lx) * vx0 * ((x0c == bx + 1) ? 1.f : 0.f)
                   + lx * vx1 * ((x1c == bx + 1) ? 1.f : 0.f);
    const float a0 = (1.f - ly) * fy0;
    const float a1 = ly * fy1;
    qw[tap][pl] = make_float4(wl * a0, wr * a0, wl * a1, wr * a1);
    qi[tap][pl] = make_int2((((y0c << 6) + bx) << 2), (((y1c << 6) + bx) << 2));
  }
  __syncthreads();

  float accB[9];
#pragma unroll
  for (int i = 0; i < 9; ++i) accB[i] = 0.f;

  const int cbase = __builtin_amdgcn_readfirstlane(wave * 8);
  for (int cc = 0; cc < 8; ++cc) {
    const int c = cbase + cc;
    const char* p = (const char*)(depth + (((n << 6) + c) << 12));
    const float* wp = mask_w + c * 9;   // wave-uniform
#pragma unroll
    for (int tap = 0; tap < 9; ++tap) {
      const float4 w4 = qw[tap][lane];
      const int2 ii   = qi[tap][lane];
      const float2_u pa = *(const float2_u*)(p + ii.x);
      const float2_u pb = *(const float2_u*)(p + ii.y);
      const float val = pa.x * w4.x + pa.y * w4.y + pb.x * w4.z + pb.y * w4.w;
#pragma unroll
      for (int co = 0; co < 9; ++co) accB[co] += val * wp[co * 576 + tap];
    }
  }
#pragma unroll
  for (int co = 0; co < 9; ++co) redB[wave][co][lane] = accB[co];
  __syncthreads();
  for (int o = tid; o < 9 * 64; o += 512) {
    const int co = o >> 6, w2 = o & 63;
    float s = mask_b[co];
#pragma unroll
    for (int w = 0; w < 8; ++w) s += redB[w][co][w2];
    mask[((n * 9 + co) << 12) + (ho << 6) + w2] = 1.f / (1.f + expf(-s));
  }
}

// ---------------------------------------------------------------------------
// K3: main modulated deform conv, bf16 MFMA GEMM, channel-major K, split-K x4.
// Grid 1024: b&7 = XCD (32-row strip of one batch); (b>>3)&3 = K-quarter.
// Epilogue: fixed-point int32 atomicAdd into pre-zeroed out (deterministic).
// ---------------------------------------------------------------------------
__global__ __launch_bounds__(512, 8) void k_deform_gemm(
    const float* __restrict__ x, const float* __restrict__ offs,
    const float* __restrict__ mask, const unsigned short* __restrict__ wbf,
    const float* __restrict__ bias, int* __restrict__ outi)
{
  __shared__ __align__(16) unsigned short Bs[2][64][72];  // 18432 B
  __shared__ float4 pwT[9][64];   // [tap][px] remapped weights  9216 B
  __shared__ int2   piT[9][64];   // [tap][px] byte offsets      4608 B

  const int tid = threadIdx.x;
  const int b    = blockIdx.x;                    // 0..1023
  const int xcd  = b & 7;
  const int s    = b >> 3;                        // 0..127
  const int kq   = s & 3;                         // K-quarter
  const int rs   = s >> 2;                        // 0..31
  const int n    = xcd >> 1;
  const int ho0  = ((xcd & 1) << 5) + rs;         // 0..63
  const int pxb  = ho0 << 6;

  // phase 0: sampling params for 64 px x 9 taps (e = tap*64 + pl)
  for (int e = tid; e < 576; e += 512) {
    const int tap = e >> 6, pl = e & 63;
    const float dy = offs[((n * 18 + 2 * tap) << 12) + pxb + pl];
    const float dx = offs[((n * 18 + 2 * tap + 1) << 12) + pxb + pl];
    const float m  = mask[((n * 9 + tap) << 12) + pxb + pl];
    const float yy = (float)(ho0 - 1 + tap / 3) + dy;
    const float xx = (float)(pl - 1 + tap % 3) + dx;
    const float y0f = floorf(yy), x0f = floorf(xx);
    const float ly = yy - y0f, lx = xx - x0f;
    const int y0 = (int)y0f, x0 = (int)x0f;
    const int y0c = min(max(y0, 0), 63);
    const int y1c = min(max(y0 + 1, 0), 63);
    const float fy0 = (y0 >= 0 && y0 < 64) ? 1.f : 0.f;
    const float fy1 = (y0 >= -1 && y0 < 63) ? 1.f : 0.f;
    const int x0c = min(max(x0, 0), 63);
    const int x1c = min(max(x0 + 1, 0), 63);
    const int bx  = min(max(x0, 0), 62);
    const float vx0 = (x0 >= 0 && x0 < 64) ? 1.f : 0.f;
    const float vx1 = (x0 >= -1 && x0 < 63) ? 1.f : 0.f;
    const float wl = (1.f - lx) * vx0 * ((x0c == bx) ? 1.f : 0.f)
                   + lx * vx1 * ((x1c == bx) ? 1.f : 0.f);
    const float wr = (1.f - lx) * vx0 * ((x0c == bx + 1) ? 1.f : 0.f)
                   + lx * vx1 * ((x1c == bx + 1) ? 1.f : 0.f);
    const float a0 = (1.f - ly) * fy0 * m;
    const float a1 = ly * fy1 * m;
    pwT[tap][pl] = make_float4(wl * a0, wr * a0, wl * a1, wr * a1);
    piT[tap][pl] = make_int2((((y0c << 6) + bx) << 2), (((y1c << 6) + bx) << 2));
  }
  __syncthreads();   // sample() reads pwT/piT written by other waves

  const int pxl = tid & 63;
  const int oct = tid >> 6;               // 0..7; also the wave id
  const float* xn = x + ((long)(n << 8) << 12);

  auto sample = [&](int kc, int buf) {
    const int kk0 = kc + (oct << 3);      // first k of this octet
    int c = (int)(((unsigned)kk0 * 7282u) >> 16);   // kk0/9 (magic, k<2304)
    int tap = kk0 - 9 * c;
    const char* p = (const char*)(xn + (c << 12));
    __align__(16) unsigned short v[8];
#pragma unroll
    for (int j = 0; j < 8; ++j) {
      const float4 w = pwT[tap][pxl];
      const int2 ii  = piT[tap][pxl];
      const float2_u pa = *(const float2_u*)(p + ii.x);
      const float2_u pb = *(const float2_u*)(p + ii.y);
      v[j] = f2bf(pa.x * w.x + pa.y * w.y + pb.x * w.z + pb.y * w.w);
      if (++tap == 9) { tap = 0; p += 16384; }   // next channel image
    }
    *(int4*)&Bs[buf][pxl][oct << 3] = *(const int4*)v;
  };

  f32x4 acc[2][4];
#pragma unroll
  for (int mt = 0; mt < 2; ++mt)
#pragma unroll
    for (int nt = 0; nt < 4; ++nt)
#pragma unroll
      for (int r = 0; r < 4; ++r) acc[mt][nt][r] = 0.f;

  const int kb = kq * 576;                // this block's K range: [kb, kb+576)
  sample(kb, 0);
  __syncthreads();

  const int lane = tid & 63;
  const int wv   = oct;
  const int mrow = lane & 15;
  const int koct = lane >> 4;             // 0..3 -> k-subgroup of 8

  for (int ic = 0; ic < 9; ++ic) {
    const int kc = kb + (ic << 6);
    // A fragment loads (global, L2-hot) — issue before sampling
    bf16x8 af[2][2];
#pragma unroll
    for (int mt = 0; mt < 2; ++mt)
#pragma unroll
      for (int ks = 0; ks < 2; ++ks) {
        const int row = (wv << 5) + (mt << 4) + mrow;
        const int col = kc + (ks << 5) + (koct << 3);
        af[mt][ks] = *(const bf16x8*)(wbf + row * 2304 + col);
      }

    if (ic + 1 < 9) sample(kb + ((ic + 1) << 6), (ic + 1) & 1);

    const int buf = ic & 1;
#pragma unroll
    for (int ks = 0; ks < 2; ++ks)
#pragma unroll
      for (int nt = 0; nt < 4; ++nt) {
        const bf16x8 bfr =
            *(const bf16x8*)&Bs[buf][(nt << 4) + mrow][(ks << 5) + (koct << 3)];
        acc[0][nt] = __builtin_amdgcn_mfma_f32_16x16x32_bf16(af[0][ks], bfr,
                                                             acc[0][nt], 0, 0, 0);
        acc[1][nt] = __builtin_amdgcn_mfma_f32_16x16x32_bf16(af[1][ks], bfr,
                                                             acc[1][nt], 0, 0, 0);
      }
    __syncthreads();
  }

  // epilogue: C/D layout col=lane&15 (px), row=(lane>>4)*4+r (co)
  // deterministic split-K: fixed-point int atomics; kq==0 adds bias.
#pragma unroll
  for (int mt = 0; mt < 2; ++mt)
#pragma unroll
    for (int nt = 0; nt < 4; ++nt)
#pragma unroll
      for (int r = 0; r < 4; ++r) {
        const int co = (wv << 5) + (mt << 4) + ((lane >> 4) << 2) + r;
        const int pxg = pxb + (nt << 4) + (lane & 15);
        float v = acc[mt][nt][r];
        if (kq == 0) v += bias[co];
        const int iv = __float2int_rn(v * FIXSCALE);
        atomicAdd(&outi[(((n << 8) + co) << 12) + pxg], iv);
      }
}

// ---------------------------------------------------------------------------
// K4: in-place fixed-point -> float. 4.2M elements, int4/float4 wide.
// ---------------------------------------------------------------------------
__global__ __launch_bounds__(256) void k_finalize(float* __restrict__ out)
{
  const int i = (blockIdx.x * 256 + threadIdx.x) << 2;
  int4 iv = *(const int4*)((const int*)out + i);
  float4 fv;
  fv.x = (float)iv.x * FIXINV;
  fv.y = (float)iv.y * FIXINV;
  fv.z = (float)iv.z * FIXINV;
  fv.w = (float)iv.w * FIXINV;
  *(float4*)(out + i) = fv;
}

// ---------------------------------------------------------------------------
extern "C" void kernel_launch(void* const* d_in, const int* in_sizes, int n_in,
                              void* d_out, int out_size, void* d_ws, size_t ws_size,
                              hipStream_t stream) {
  const float* x      = (const float*)d_in[0];
  const float* depth  = (const float*)d_in[1];
  const float* weight = (const float*)d_in[2];
  const float* bias   = (const float*)d_in[3];
  const float* off_w  = (const float*)d_in[4];
  const float* off_b  = (const float*)d_in[5];
  const float* mask_w = (const float*)d_in[6];
  const float* mask_b = (const float*)d_in[7];
  float* out = (float*)d_out;

  float* offs = (float*)d_ws;                       // 294912 floats
  float* mask = offs + 294912;                      // 147456 floats
  unsigned short* wbf = (unsigned short*)(mask + 147456);  // 589824 bf16

  hipMemsetAsync(out, 0, (size_t)out_size * sizeof(float), stream);
  k_prep_weight<<<2304, 256, 0, stream>>>(weight, wbf);
  k_offmask<<<256, 512, 0, stream>>>(x, depth, off_w, off_b, mask_w, mask_b,
                                     offs, mask);
  k_deform_gemm<<<1024, 512, 0, stream>>>(x, offs, mask, wbf, bias, (int*)out);
  k_finalize<<<out_size / 1024, 256, 0, stream>>>(out);
}